// Round 13
// baseline (228.586 us; speedup 1.0000x reference)
//
#include <hip/hip_runtime.h>
#include <math.h>

#define DIN 128
#define NH 4
#define HC 128
static constexpr float NEG_SLOPE = 0.2f;

typedef __attribute__((ext_vector_type(8))) short bf16x8;
typedef __attribute__((ext_vector_type(4))) float f32x4;

__device__ __forceinline__ float leaky(float x) { return x > 0.f ? x : NEG_SLOPE * x; }

// RNE float->bf16 (finite inputs)
__device__ __forceinline__ unsigned short f2bf(float f) {
  unsigned u = __float_as_uint(f);
  unsigned r = (u + 0x7fffu + ((u >> 16) & 1u)) >> 16;
  return (unsigned short)r;
}
__device__ __forceinline__ float bf_lo(unsigned u) { return __uint_as_float(u << 16); }
__device__ __forceinline__ float bf_hi(unsigned u) { return __uint_as_float(u & 0xffff0000u); }

// ---------------------------------------------------------------------------
// K0: zero cnt + pre-swizzle W into the mfma B-fragment layout.
__global__ void k_init(const float* __restrict__ W, short* __restrict__ bswz,
                       unsigned* __restrict__ cnt, int n) {
  int g = blockIdx.x * blockDim.x + threadIdx.x;
  if (g < n) cnt[g] = 0u;
  if (g < 2048) {
    int ntile = g >> 8;
    int ks = (g >> 6) & 3;
    int lane = g & 63;
    int col = (ntile << 4) + (lane & 15);
    int kb = ks * 32 + ((lane >> 4) << 3);
    bf16x8 v;
#pragma unroll
    for (int j = 0; j < 8; ++j) v[j] = (short)f2bf(W[(kb + j) * HC + col]);
    ((bf16x8*)bswz)[g] = v;
  }
}

// ---------------------------------------------------------------------------
// K1 (fused): proj blocks + count blocks interleaved 3:2 (concurrent).
__global__ __launch_bounds__(256) void k_fused(
    const float* __restrict__ x, const short* __restrict__ bswz,
    const float* __restrict__ att_s, const float* __restrict__ att_d,
    unsigned short* __restrict__ hbf,
    float* __restrict__ a_src, float* __restrict__ a_dst, int n,
    const int* __restrict__ dst,
    unsigned* __restrict__ cnt, unsigned short* __restrict__ rank,
    int E, int CB) {
  int grp = blockIdx.x / 5;
  int r = blockIdx.x % 5;
  if (r >= 3) {
    // ---- count path: one 32-bit atomic per edge, old value = rank ----
    int cid = grp * 2 + (r - 3);
    int stride = CB * 256;
    for (int e = cid * 256 + (int)threadIdx.x; e < E; e += stride) {
      unsigned old = atomicAdd(&cnt[dst[e]], 1u);
      rank[e] = (unsigned short)old;
    }
    return;
  }
  // ---- proj path ----
  int pid = grp * 3 + r;
  int wtile = pid * 4 + (threadIdx.x >> 6);
  int ntiles = n >> 4;
  if (wtile >= ntiles) return;
  int lane = threadIdx.x & 63;
  int row0 = wtile << 4;

  int arow = row0 + (lane & 15);
  int kbase = (lane >> 4) << 3;
  const float* xr = x + (size_t)arow * DIN;
  bf16x8 a[4];
#pragma unroll
  for (int ks = 0; ks < 4; ++ks) {
    float4 lo = *(const float4*)(xr + ks * 32 + kbase);
    float4 hi = *(const float4*)(xr + ks * 32 + kbase + 4);
    bf16x8 v;
    v[0] = (short)f2bf(lo.x); v[1] = (short)f2bf(lo.y);
    v[2] = (short)f2bf(lo.z); v[3] = (short)f2bf(lo.w);
    v[4] = (short)f2bf(hi.x); v[5] = (short)f2bf(hi.y);
    v[6] = (short)f2bf(hi.z); v[7] = (short)f2bf(hi.w);
    a[ks] = v;
  }

  const bf16x8* B = (const bf16x8*)bswz;
  int crow_base = row0 + ((lane >> 4) << 2);
  int ccol_off = lane & 15;

  float ra[4] = {0.f, 0.f, 0.f, 0.f};
  float rd[4] = {0.f, 0.f, 0.f, 0.f};

#pragma unroll
  for (int ntile = 0; ntile < 8; ++ntile) {
    f32x4 acc = {0.f, 0.f, 0.f, 0.f};
#pragma unroll
    for (int ks = 0; ks < 4; ++ks)
      acc = __builtin_amdgcn_mfma_f32_16x16x32_bf16(a[ks], B[(ntile * 4 + ks) * 64 + lane], acc, 0, 0, 0);
    int col = (ntile << 4) + ccol_off;
    float as = att_s[col], ad = att_d[col];
#pragma unroll
    for (int i = 0; i < 4; ++i) {
      hbf[(size_t)(crow_base + i) * HC + col] = f2bf(acc[i]);
      ra[i] = fmaf(acc[i], as, ra[i]);
      rd[i] = fmaf(acc[i], ad, rd[i]);
    }
    if (ntile & 1) {
      int hh = ntile >> 1;
#pragma unroll
      for (int i = 0; i < 4; ++i) {
#pragma unroll
        for (int m = 1; m <= 8; m <<= 1) {
          ra[i] += __shfl_xor(ra[i], m, 64);
          rd[i] += __shfl_xor(rd[i], m, 64);
        }
        if ((lane & 15) == 0) {
          a_src[(crow_base + i) * NH + hh] = ra[i];
          a_dst[(crow_base + i) * NH + hh] = rd[i];
        }
        ra[i] = 0.f; rd[i] = 0.f;
      }
    }
  }
}

// ---------------------------------------------------------------------------
// scan1: scans 8-PADDED counts (ceil8) into off (exclusive), chunk total -> bsum
__global__ __launch_bounds__(256) void k_scan1(const unsigned* __restrict__ cnt,
                                               int* __restrict__ off,
                                               int* __restrict__ bsum, int n) {
  __shared__ int lds[256];
  int b = blockIdx.x, t = threadIdx.x;
  int base = b * 1024 + t * 4;
  int v0 = 0, v1 = 0, v2 = 0, v3 = 0;
  if (base + 0 < n) v0 = ((int)cnt[base + 0] + 7) & ~7;
  if (base + 1 < n) v1 = ((int)cnt[base + 1] + 7) & ~7;
  if (base + 2 < n) v2 = ((int)cnt[base + 2] + 7) & ~7;
  if (base + 3 < n) v3 = ((int)cnt[base + 3] + 7) & ~7;
  int s = v0 + v1 + v2 + v3;
  lds[t] = s;
  __syncthreads();
  for (int ofs = 1; ofs < 256; ofs <<= 1) {
    int x = (t >= ofs) ? lds[t - ofs] : 0;
    __syncthreads();
    lds[t] += x;
    __syncthreads();
  }
  int run = (t > 0) ? lds[t - 1] : 0;
  if (t == 255) bsum[b] = lds[255];
  if (base + 0 < n) { off[base + 0] = run; run += v0; }
  if (base + 1 < n) { off[base + 1] = run; run += v1; }
  if (base + 2 < n) { off[base + 2] = run; run += v2; }
  if (base + 3 < n) { off[base + 3] = run; run += v3; }
}

__global__ __launch_bounds__(256) void k_scan2(int* __restrict__ bsum, int nb) {
  __shared__ int lds[256];
  int t = threadIdx.x;
  lds[t] = (t < nb) ? bsum[t] : 0;
  __syncthreads();
  for (int ofs = 1; ofs < 256; ofs <<= 1) {
    int x = (t >= ofs) ? lds[t - ofs] : 0;
    __syncthreads();
    lds[t] += x;
    __syncthreads();
  }
  int excl = (t > 0) ? lds[t - 1] : 0;
  if (t < nb) bsum[t] = excl;
}

// ---------------------------------------------------------------------------
// scatter: pure permute, NO atomics, NO exp. edges2[p] = {src, bits(w)}.
// Slots beyond cnt within each 8-aligned segment stay zero (dummy edges:
// w=0 -> et=exp(-inf)=0 -> contribute nothing).
__global__ void k_scatter(const int* __restrict__ ei, const float* __restrict__ w,
                          const int* __restrict__ off, const int* __restrict__ bsum,
                          const unsigned short* __restrict__ rank,
                          int2* __restrict__ edges2, int E) {
  int e = blockIdx.x * blockDim.x + threadIdx.x;
  if (e >= E) return;
  int s = ei[e], d = ei[E + e];
  int p = off[d] + bsum[d >> 10] + (int)rank[e];
  edges2[p] = make_int2(s, __float_as_int(w[e]));
}

// ---------------------------------------------------------------------------
// gather-aggregate: ONE wave per node; lane owns channels (2t,2t+1).
// Segments are 8-padded -> NO tail path, uniform control flow, ~17% fewer
// slots than 16-padding. 8-edge chunks: stage on lanes (t&7); exp on lanes
// 0..31 as (edge=(t>>2)&7, head=t&3); R9-proven interleaved load+fma body.
__global__ __launch_bounds__(256) void k_gather(
    const int2* __restrict__ edges2,
    const int* __restrict__ off, const int* __restrict__ bsum,
    const unsigned* __restrict__ cnt,
    const float* __restrict__ a_src, const float* __restrict__ a_dst,
    const unsigned short* __restrict__ hbf, const float* __restrict__ bias,
    float* __restrict__ out, int n) {
  int node = blockIdx.x * 4 + (threadIdx.x >> 6);
  if (node >= n) return;
  int t = threadIdx.x & 63;
  int j2 = t * 2;          // output channels j2, j2+1 (head hh = t>>4)
  int hh = t >> 4;
  int t7 = t & 7, q = (t >> 2) & 7, h4 = t & 3;
  int beg = off[node] + bsum[node >> 10];
  int deg = (int)cnt[node];
  int end = beg + ((deg + 7) & ~7);

  float adq = a_dst[node * NH + h4];   // a_dst for head (t&3) (exp path)
  // issue self-loop loads early (independent of the loop)
  unsigned us = *(const unsigned*)(hbf + (size_t)node * HC + j2);
  float a_s_self = a_src[node * NH + hh];
  float a_d_self = a_dst[node * NH + hh];
  float acc0 = 0.f, acc1 = 0.f, den = 0.f, wacc = 0.f;

  for (int c = beg; c < end; c += 8) {
    int2 ev = edges2[c + t7];
    int sq = __shfl(ev.x, q, 64);                      // src of edge c+q
    float wq = __int_as_float(__shfl(ev.y, q, 64));
    float asq = a_src[sq * NH + h4];
    float et = expf(leaky(asq + adq) + log2f(wq));     // dummy: w=0 -> et=0
    wacc += (h4 == 0 && t < 32) ? wq : 0.f;            // count each edge once
#pragma unroll
    for (int j = 0; j < 8; ++j) {
      int s = __shfl(ev.x, j, 64);
      float e = __shfl(et, j * 4 + hh, 64);
      unsigned u = *(const unsigned*)(hbf + (size_t)s * HC + j2);
      den += e;
      acc0 = fmaf(e, bf_lo(u), acc0);
      acc1 = fmaf(e, bf_hi(u), acc1);
    }
  }

  // wsum across wave (8 contributing lanes: h4==0, t<32)
#pragma unroll
  for (int m = 1; m <= 32; m <<= 1) wacc += __shfl_xor(wacc, m, 64);

  float lw = deg > 0 ? wacc / (float)deg : 1.f;
  float exs = expf(leaky(a_s_self + a_d_self) + log2f(lw));
  den += exs;
  acc0 = fmaf(exs, bf_lo(us), acc0);
  acc1 = fmaf(exs, bf_hi(us), acc1);
  float rden = 1.f / den;
  float2 o;
  o.x = acc0 * rden + bias[j2];
  o.y = acc1 * rden + bias[j2 + 1];
  *(float2*)(out + (size_t)node * HC + j2) = o;
}

// ---------------------------------------------------------------------------
extern "C" void kernel_launch(void* const* d_in, const int* in_sizes, int n_in,
                              void* d_out, int out_size, void* d_ws, size_t ws_size,
                              hipStream_t stream) {
  const float* x       = (const float*)d_in[0];
  const int*   ei      = (const int*)d_in[1];   // [2][E]
  const float* eattr   = (const float*)d_in[2];
  const float* W       = (const float*)d_in[3];
  const float* att_src = (const float*)d_in[4];
  const float* att_dst = (const float*)d_in[5];
  const float* bias    = (const float*)d_in[6];
  float* out = (float*)d_out;

  const int n = in_sizes[0] / DIN;
  const int E = in_sizes[2];
  const size_t EPAD = (size_t)E + (size_t)n * 7;   // upper bound on padded slots

  // workspace layout (all boundaries 8/16B aligned: n, E even)
  unsigned short* hbf = (unsigned short*)d_ws;            // n*HC bf16 (25.6 MB)
  int2*   edges2 = (int2*)(hbf + (size_t)n * HC);         // EPAD int2 (~18.4 MB)
  float*  a_src  = (float*)(edges2 + EPAD);               // n*4
  float*  a_dst  = a_src + (size_t)n * NH;                // n*4
  short*  bswz   = (short*)(a_dst + (size_t)n * NH);      // 16384 bf16 (32 KB)
  unsigned* cnt  = (unsigned*)(bswz + 16384);             // n u32
  int*    off    = (int*)(cnt + n);                       // n
  unsigned short* rank = (unsigned short*)(off + n);      // E u16
  int*    bsum   = (int*)(rank + E);                      // <=256

  const int* dst_idx = ei + E;
  int nb = (n + 1023) / 1024;
  int wavetiles = n >> 4;                 // n % 16 == 0
  int PB = (wavetiles + 3) / 4;           // proj blocks (4 waves each)
  int PB3 = ((PB + 2) / 3) * 3;
  int CB = 2 * (PB3 / 3);                 // count blocks (3:2 interleave)
  int grid = PB3 + CB;

  hipMemsetAsync(edges2, 0, EPAD * sizeof(int2), stream);  // dummy edges = {0, 0.0f}
  k_init<<<(n + 255) / 256, 256, 0, stream>>>(W, bswz, cnt, n);
  k_fused<<<grid, 256, 0, stream>>>(x, bswz, att_src, att_dst, hbf, a_src, a_dst, n,
                                    dst_idx, cnt, rank, E, CB);
  k_scan1<<<nb, 256, 0, stream>>>(cnt, off, bsum, n);
  k_scan2<<<1, 256, 0, stream>>>(bsum, nb);
  k_scatter<<<(E + 255) / 256, 256, 0, stream>>>(ei, eattr, off, bsum, rank, edges2, E);
  k_gather<<<(n + 3) / 4, 256, 0, stream>>>(edges2, off, bsum, cnt, a_src, a_dst,
                                            hbf, bias, out, n);
}

// Round 14
// 218.258 us; speedup vs baseline: 1.0473x; 1.0473x over previous
//
#include <hip/hip_runtime.h>
#include <math.h>

#define DIN 128
#define NH 4
#define HC 128
static constexpr float NEG_SLOPE = 0.2f;

typedef __attribute__((ext_vector_type(8))) short bf16x8;
typedef __attribute__((ext_vector_type(4))) float f32x4;

__device__ __forceinline__ float leaky(float x) { return x > 0.f ? x : NEG_SLOPE * x; }

// RNE float->bf16 (finite inputs)
__device__ __forceinline__ unsigned short f2bf(float f) {
  unsigned u = __float_as_uint(f);
  unsigned r = (u + 0x7fffu + ((u >> 16) & 1u)) >> 16;
  return (unsigned short)r;
}
__device__ __forceinline__ float bf_lo(unsigned u) { return __uint_as_float(u << 16); }
__device__ __forceinline__ float bf_hi(unsigned u) { return __uint_as_float(u & 0xffff0000u); }

// ---------------------------------------------------------------------------
// K0: zero cnt + pre-swizzle W into the mfma B-fragment layout.
__global__ void k_init(const float* __restrict__ W, short* __restrict__ bswz,
                       unsigned* __restrict__ cnt, int n) {
  int g = blockIdx.x * blockDim.x + threadIdx.x;
  if (g < n) cnt[g] = 0u;
  if (g < 2048) {
    int ntile = g >> 8;
    int ks = (g >> 6) & 3;
    int lane = g & 63;
    int col = (ntile << 4) + (lane & 15);
    int kb = ks * 32 + ((lane >> 4) << 3);
    bf16x8 v;
#pragma unroll
    for (int j = 0; j < 8; ++j) v[j] = (short)f2bf(W[(kb + j) * HC + col]);
    ((bf16x8*)bswz)[g] = v;
  }
}

// ---------------------------------------------------------------------------
// K1 (fused): proj blocks + count blocks interleaved 3:2 (concurrent).
__global__ __launch_bounds__(256) void k_fused(
    const float* __restrict__ x, const short* __restrict__ bswz,
    const float* __restrict__ att_s, const float* __restrict__ att_d,
    unsigned short* __restrict__ hbf,
    float* __restrict__ a_src, float* __restrict__ a_dst, int n,
    const int* __restrict__ dst,
    unsigned* __restrict__ cnt, unsigned short* __restrict__ rank,
    int E, int CB) {
  int grp = blockIdx.x / 5;
  int r = blockIdx.x % 5;
  if (r >= 3) {
    // ---- count path: one 32-bit atomic per edge, old value = rank ----
    int cid = grp * 2 + (r - 3);
    int stride = CB * 256;
    for (int e = cid * 256 + (int)threadIdx.x; e < E; e += stride) {
      unsigned old = atomicAdd(&cnt[dst[e]], 1u);
      rank[e] = (unsigned short)old;
    }
    return;
  }
  // ---- proj path ----
  int pid = grp * 3 + r;
  int wtile = pid * 4 + (threadIdx.x >> 6);
  int ntiles = n >> 4;
  if (wtile >= ntiles) return;
  int lane = threadIdx.x & 63;
  int row0 = wtile << 4;

  int arow = row0 + (lane & 15);
  int kbase = (lane >> 4) << 3;
  const float* xr = x + (size_t)arow * DIN;
  bf16x8 a[4];
#pragma unroll
  for (int ks = 0; ks < 4; ++ks) {
    float4 lo = *(const float4*)(xr + ks * 32 + kbase);
    float4 hi = *(const float4*)(xr + ks * 32 + kbase + 4);
    bf16x8 v;
    v[0] = (short)f2bf(lo.x); v[1] = (short)f2bf(lo.y);
    v[2] = (short)f2bf(lo.z); v[3] = (short)f2bf(lo.w);
    v[4] = (short)f2bf(hi.x); v[5] = (short)f2bf(hi.y);
    v[6] = (short)f2bf(hi.z); v[7] = (short)f2bf(hi.w);
    a[ks] = v;
  }

  const bf16x8* B = (const bf16x8*)bswz;
  int crow_base = row0 + ((lane >> 4) << 2);
  int ccol_off = lane & 15;

  float ra[4] = {0.f, 0.f, 0.f, 0.f};
  float rd[4] = {0.f, 0.f, 0.f, 0.f};

#pragma unroll
  for (int ntile = 0; ntile < 8; ++ntile) {
    f32x4 acc = {0.f, 0.f, 0.f, 0.f};
#pragma unroll
    for (int ks = 0; ks < 4; ++ks)
      acc = __builtin_amdgcn_mfma_f32_16x16x32_bf16(a[ks], B[(ntile * 4 + ks) * 64 + lane], acc, 0, 0, 0);
    int col = (ntile << 4) + ccol_off;
    float as = att_s[col], ad = att_d[col];
#pragma unroll
    for (int i = 0; i < 4; ++i) {
      hbf[(size_t)(crow_base + i) * HC + col] = f2bf(acc[i]);
      ra[i] = fmaf(acc[i], as, ra[i]);
      rd[i] = fmaf(acc[i], ad, rd[i]);
    }
    if (ntile & 1) {
      int hh = ntile >> 1;
#pragma unroll
      for (int i = 0; i < 4; ++i) {
#pragma unroll
        for (int m = 1; m <= 8; m <<= 1) {
          ra[i] += __shfl_xor(ra[i], m, 64);
          rd[i] += __shfl_xor(rd[i], m, 64);
        }
        if ((lane & 15) == 0) {
          a_src[(crow_base + i) * NH + hh] = ra[i];
          a_dst[(crow_base + i) * NH + hh] = rd[i];
        }
        ra[i] = 0.f; rd[i] = 0.f;
      }
    }
  }
}

// ---------------------------------------------------------------------------
// scan1: scans 16-PADDED counts (ceil16) into off (exclusive), chunk total -> bsum
__global__ __launch_bounds__(256) void k_scan1(const unsigned* __restrict__ cnt,
                                               int* __restrict__ off,
                                               int* __restrict__ bsum, int n) {
  __shared__ int lds[256];
  int b = blockIdx.x, t = threadIdx.x;
  int base = b * 1024 + t * 4;
  int v0 = 0, v1 = 0, v2 = 0, v3 = 0;
  if (base + 0 < n) v0 = ((int)cnt[base + 0] + 15) & ~15;
  if (base + 1 < n) v1 = ((int)cnt[base + 1] + 15) & ~15;
  if (base + 2 < n) v2 = ((int)cnt[base + 2] + 15) & ~15;
  if (base + 3 < n) v3 = ((int)cnt[base + 3] + 15) & ~15;
  int s = v0 + v1 + v2 + v3;
  lds[t] = s;
  __syncthreads();
  for (int ofs = 1; ofs < 256; ofs <<= 1) {
    int x = (t >= ofs) ? lds[t - ofs] : 0;
    __syncthreads();
    lds[t] += x;
    __syncthreads();
  }
  int run = (t > 0) ? lds[t - 1] : 0;
  if (t == 255) bsum[b] = lds[255];
  if (base + 0 < n) { off[base + 0] = run; run += v0; }
  if (base + 1 < n) { off[base + 1] = run; run += v1; }
  if (base + 2 < n) { off[base + 2] = run; run += v2; }
  if (base + 3 < n) { off[base + 3] = run; run += v3; }
}

__global__ __launch_bounds__(256) void k_scan2(int* __restrict__ bsum, int nb) {
  __shared__ int lds[256];
  int t = threadIdx.x;
  lds[t] = (t < nb) ? bsum[t] : 0;
  __syncthreads();
  for (int ofs = 1; ofs < 256; ofs <<= 1) {
    int x = (t >= ofs) ? lds[t - ofs] : 0;
    __syncthreads();
    lds[t] += x;
    __syncthreads();
  }
  int excl = (t > 0) ? lds[t - 1] : 0;
  if (t < nb) bsum[t] = excl;
}

// ---------------------------------------------------------------------------
// scatter: pure permute, NO atomics, NO exp. edges2[p] = {src, bits(w)}.
// One-shot input streams read non-temporally (don't pollute L2).
__global__ void k_scatter(const int* __restrict__ ei, const float* __restrict__ w,
                          const int* __restrict__ off, const int* __restrict__ bsum,
                          const unsigned short* __restrict__ rank,
                          int2* __restrict__ edges2, int E) {
  int e = blockIdx.x * blockDim.x + threadIdx.x;
  if (e >= E) return;
  int s = __builtin_nontemporal_load(ei + e);
  int d = __builtin_nontemporal_load(ei + E + e);
  float wv = __builtin_nontemporal_load(w + e);
  unsigned short rk = __builtin_nontemporal_load(rank + e);
  int p = off[d] + bsum[d >> 10] + (int)rk;
  edges2[p] = make_int2(s, __float_as_int(wv));
}

// ---------------------------------------------------------------------------
// gather-aggregate: ONE wave per node; lane owns channels (2t,2t+1).
// 16-padded segments (R12-proven structure). Stage loads non-temporal
// (streamed once); out stores non-temporal (never re-read) -> keep L2 for h.
__global__ __launch_bounds__(256) void k_gather(
    const int2* __restrict__ edges2,
    const int* __restrict__ off, const int* __restrict__ bsum,
    const unsigned* __restrict__ cnt,
    const float* __restrict__ a_src, const float* __restrict__ a_dst,
    const unsigned short* __restrict__ hbf, const float* __restrict__ bias,
    float* __restrict__ out, int n) {
  int node = blockIdx.x * 4 + (threadIdx.x >> 6);
  if (node >= n) return;
  int t = threadIdx.x & 63;
  int j2 = t * 2;          // output channels j2, j2+1 (head hh = t>>4)
  int hh = t >> 4;
  int t15 = t & 15, q = t >> 2, h4 = t & 3;
  int beg = off[node] + bsum[node >> 10];
  int deg = (int)cnt[node];
  int end = beg + ((deg + 15) & ~15);

  float adq = a_dst[node * NH + h4];   // a_dst for head (t&3) (exp path)
  unsigned us = *(const unsigned*)(hbf + (size_t)node * HC + j2);
  float a_s_self = a_src[node * NH + hh];
  float a_d_self = a_dst[node * NH + hh];
  float acc0 = 0.f, acc1 = 0.f, den = 0.f, wacc = 0.f;

  const unsigned long long* e8 = (const unsigned long long*)edges2;
  for (int c = beg; c < end; c += 16) {
    unsigned long long evu = __builtin_nontemporal_load(e8 + c + t15);
    int evx = (int)(unsigned)(evu & 0xffffffffull);
    int evy = (int)(unsigned)(evu >> 32);
    int sq = __shfl(evx, q, 64);                       // src of edge c+(t>>2)
    float wq = __int_as_float(__shfl(evy, q, 64));
    float asq = a_src[sq * NH + h4];
    float et = expf(leaky(asq + adq) + log2f(wq));     // dummy: w=0 -> et=0
    wacc += (h4 == 0) ? wq : 0.f;
#pragma unroll
    for (int j = 0; j < 16; ++j) {
      int s = __shfl(evx, j, 64);
      float e = __shfl(et, j * 4 + hh, 64);
      unsigned u = *(const unsigned*)(hbf + (size_t)s * HC + j2);
      den += e;
      acc0 = fmaf(e, bf_lo(u), acc0);
      acc1 = fmaf(e, bf_hi(u), acc1);
    }
  }

  // wsum across wave (each real edge counted once by its (t&3)==0 lane)
#pragma unroll
  for (int m = 1; m <= 32; m <<= 1) wacc += __shfl_xor(wacc, m, 64);

  float lw = deg > 0 ? wacc / (float)deg : 1.f;
  float exs = expf(leaky(a_s_self + a_d_self) + log2f(lw));
  den += exs;
  acc0 = fmaf(exs, bf_lo(us), acc0);
  acc1 = fmaf(exs, bf_hi(us), acc1);
  float rden = 1.f / den;
  float o0 = acc0 * rden + bias[j2];
  float o1 = acc1 * rden + bias[j2 + 1];
  float* op = out + (size_t)node * HC + j2;
  __builtin_nontemporal_store(o0, op);
  __builtin_nontemporal_store(o1, op + 1);
}

// ---------------------------------------------------------------------------
extern "C" void kernel_launch(void* const* d_in, const int* in_sizes, int n_in,
                              void* d_out, int out_size, void* d_ws, size_t ws_size,
                              hipStream_t stream) {
  const float* x       = (const float*)d_in[0];
  const int*   ei      = (const int*)d_in[1];   // [2][E]
  const float* eattr   = (const float*)d_in[2];
  const float* W       = (const float*)d_in[3];
  const float* att_src = (const float*)d_in[4];
  const float* att_dst = (const float*)d_in[5];
  const float* bias    = (const float*)d_in[6];
  float* out = (float*)d_out;

  const int n = in_sizes[0] / DIN;
  const int E = in_sizes[2];
  const size_t EPAD = (size_t)E + (size_t)n * 15;   // upper bound on padded slots

  // workspace layout (all boundaries 8/16B aligned: n, E even)
  unsigned short* hbf = (unsigned short*)d_ws;            // n*HC bf16 (25.6 MB)
  int2*   edges2 = (int2*)(hbf + (size_t)n * HC);         // EPAD int2 (~24.8 MB)
  float*  a_src  = (float*)(edges2 + EPAD);               // n*4
  float*  a_dst  = a_src + (size_t)n * NH;                // n*4
  short*  bswz   = (short*)(a_dst + (size_t)n * NH);      // 16384 bf16 (32 KB)
  unsigned* cnt  = (unsigned*)(bswz + 16384);             // n u32
  int*    off    = (int*)(cnt + n);                       // n
  unsigned short* rank = (unsigned short*)(off + n);      // E u16
  int*    bsum   = (int*)(rank + E);                      // <=256

  const int* dst_idx = ei + E;
  int nb = (n + 1023) / 1024;
  int wavetiles = n >> 4;                 // n % 16 == 0
  int PB = (wavetiles + 3) / 4;           // proj blocks (4 waves each)
  int PB3 = ((PB + 2) / 3) * 3;
  int CB = 2 * (PB3 / 3);                 // count blocks (3:2 interleave)
  int grid = PB3 + CB;

  hipMemsetAsync(edges2, 0, EPAD * sizeof(int2), stream);  // dummy edges = {0, 0.0f}
  k_init<<<(n + 255) / 256, 256, 0, stream>>>(W, bswz, cnt, n);
  k_fused<<<grid, 256, 0, stream>>>(x, bswz, att_src, att_dst, hbf, a_src, a_dst, n,
                                    dst_idx, cnt, rank, E, CB);
  k_scan1<<<nb, 256, 0, stream>>>(cnt, off, bsum, n);
  k_scan2<<<1, 256, 0, stream>>>(bsum, nb);
  k_scatter<<<(E + 255) / 256, 256, 0, stream>>>(ei, eattr, off, bsum, rank, edges2, E);
  k_gather<<<(n + 3) / 4, 256, 0, stream>>>(edges2, off, bsum, cnt, a_src, a_dst,
                                            hbf, bias, out, n);
}

// Round 15
// 194.872 us; speedup vs baseline: 1.1730x; 1.1200x over previous
//
#include <hip/hip_runtime.h>
#include <math.h>

#define DIN 128
#define NH 4
#define HC 128
static constexpr float NEG_SLOPE = 0.2f;

typedef __attribute__((ext_vector_type(8))) short bf16x8;
typedef __attribute__((ext_vector_type(4))) float f32x4;

__device__ __forceinline__ float leaky(float x) { return x > 0.f ? x : NEG_SLOPE * x; }

// RNE float->bf16 (finite inputs)
__device__ __forceinline__ unsigned short f2bf(float f) {
  unsigned u = __float_as_uint(f);
  unsigned r = (u + 0x7fffu + ((u >> 16) & 1u)) >> 16;
  return (unsigned short)r;
}
__device__ __forceinline__ float bf_lo(unsigned u) { return __uint_as_float(u << 16); }
__device__ __forceinline__ float bf_hi(unsigned u) { return __uint_as_float(u & 0xffff0000u); }

// ---------------------------------------------------------------------------
// K0: zero cnt + pre-swizzle W into the mfma B-fragment layout.
__global__ void k_init(const float* __restrict__ W, short* __restrict__ bswz,
                       unsigned* __restrict__ cnt, int n) {
  int g = blockIdx.x * blockDim.x + threadIdx.x;
  if (g < n) cnt[g] = 0u;
  if (g < 2048) {
    int ntile = g >> 8;
    int ks = (g >> 6) & 3;
    int lane = g & 63;
    int col = (ntile << 4) + (lane & 15);
    int kb = ks * 32 + ((lane >> 4) << 3);
    bf16x8 v;
#pragma unroll
    for (int j = 0; j < 8; ++j) v[j] = (short)f2bf(W[(kb + j) * HC + col]);
    ((bf16x8*)bswz)[g] = v;
  }
}

// ---------------------------------------------------------------------------
// K1 (fused): proj blocks + count blocks interleaved 3:2 (concurrent).
__global__ __launch_bounds__(256) void k_fused(
    const float* __restrict__ x, const short* __restrict__ bswz,
    const float* __restrict__ att_s, const float* __restrict__ att_d,
    unsigned short* __restrict__ hbf,
    float* __restrict__ a_src, float* __restrict__ a_dst, int n,
    const int* __restrict__ dst,
    unsigned* __restrict__ cnt, unsigned short* __restrict__ rank,
    int E, int CB) {
  int grp = blockIdx.x / 5;
  int r = blockIdx.x % 5;
  if (r >= 3) {
    // ---- count path: one 32-bit atomic per edge, old value = rank ----
    int cid = grp * 2 + (r - 3);
    int stride = CB * 256;
    for (int e = cid * 256 + (int)threadIdx.x; e < E; e += stride) {
      unsigned old = atomicAdd(&cnt[dst[e]], 1u);
      rank[e] = (unsigned short)old;
    }
    return;
  }
  // ---- proj path ----
  int pid = grp * 3 + r;
  int wtile = pid * 4 + (threadIdx.x >> 6);
  int ntiles = n >> 4;
  if (wtile >= ntiles) return;
  int lane = threadIdx.x & 63;
  int row0 = wtile << 4;

  int arow = row0 + (lane & 15);
  int kbase = (lane >> 4) << 3;
  const float* xr = x + (size_t)arow * DIN;
  bf16x8 a[4];
#pragma unroll
  for (int ks = 0; ks < 4; ++ks) {
    float4 lo = *(const float4*)(xr + ks * 32 + kbase);
    float4 hi = *(const float4*)(xr + ks * 32 + kbase + 4);
    bf16x8 v;
    v[0] = (short)f2bf(lo.x); v[1] = (short)f2bf(lo.y);
    v[2] = (short)f2bf(lo.z); v[3] = (short)f2bf(lo.w);
    v[4] = (short)f2bf(hi.x); v[5] = (short)f2bf(hi.y);
    v[6] = (short)f2bf(hi.z); v[7] = (short)f2bf(hi.w);
    a[ks] = v;
  }

  const bf16x8* B = (const bf16x8*)bswz;
  int crow_base = row0 + ((lane >> 4) << 2);
  int ccol_off = lane & 15;

  float ra[4] = {0.f, 0.f, 0.f, 0.f};
  float rd[4] = {0.f, 0.f, 0.f, 0.f};

#pragma unroll
  for (int ntile = 0; ntile < 8; ++ntile) {
    f32x4 acc = {0.f, 0.f, 0.f, 0.f};
#pragma unroll
    for (int ks = 0; ks < 4; ++ks)
      acc = __builtin_amdgcn_mfma_f32_16x16x32_bf16(a[ks], B[(ntile * 4 + ks) * 64 + lane], acc, 0, 0, 0);
    int col = (ntile << 4) + ccol_off;
    float as = att_s[col], ad = att_d[col];
#pragma unroll
    for (int i = 0; i < 4; ++i) {
      hbf[(size_t)(crow_base + i) * HC + col] = f2bf(acc[i]);
      ra[i] = fmaf(acc[i], as, ra[i]);
      rd[i] = fmaf(acc[i], ad, rd[i]);
    }
    if (ntile & 1) {
      int hh = ntile >> 1;
#pragma unroll
      for (int i = 0; i < 4; ++i) {
#pragma unroll
        for (int m = 1; m <= 8; m <<= 1) {
          ra[i] += __shfl_xor(ra[i], m, 64);
          rd[i] += __shfl_xor(rd[i], m, 64);
        }
        if ((lane & 15) == 0) {
          a_src[(crow_base + i) * NH + hh] = ra[i];
          a_dst[(crow_base + i) * NH + hh] = rd[i];
        }
        ra[i] = 0.f; rd[i] = 0.f;
      }
    }
  }
}

// ---------------------------------------------------------------------------
// scan1: scans 16-PADDED counts (ceil16) into off (exclusive), chunk total -> bsum
__global__ __launch_bounds__(256) void k_scan1(const unsigned* __restrict__ cnt,
                                               int* __restrict__ off,
                                               int* __restrict__ bsum, int n) {
  __shared__ int lds[256];
  int b = blockIdx.x, t = threadIdx.x;
  int base = b * 1024 + t * 4;
  int v0 = 0, v1 = 0, v2 = 0, v3 = 0;
  if (base + 0 < n) v0 = ((int)cnt[base + 0] + 15) & ~15;
  if (base + 1 < n) v1 = ((int)cnt[base + 1] + 15) & ~15;
  if (base + 2 < n) v2 = ((int)cnt[base + 2] + 15) & ~15;
  if (base + 3 < n) v3 = ((int)cnt[base + 3] + 15) & ~15;
  int s = v0 + v1 + v2 + v3;
  lds[t] = s;
  __syncthreads();
  for (int ofs = 1; ofs < 256; ofs <<= 1) {
    int x = (t >= ofs) ? lds[t - ofs] : 0;
    __syncthreads();
    lds[t] += x;
    __syncthreads();
  }
  int run = (t > 0) ? lds[t - 1] : 0;
  if (t == 255) bsum[b] = lds[255];
  if (base + 0 < n) { off[base + 0] = run; run += v0; }
  if (base + 1 < n) { off[base + 1] = run; run += v1; }
  if (base + 2 < n) { off[base + 2] = run; run += v2; }
  if (base + 3 < n) { off[base + 3] = run; run += v3; }
}

__global__ __launch_bounds__(256) void k_scan2(int* __restrict__ bsum, int nb) {
  __shared__ int lds[256];
  int t = threadIdx.x;
  lds[t] = (t < nb) ? bsum[t] : 0;
  __syncthreads();
  for (int ofs = 1; ofs < 256; ofs <<= 1) {
    int x = (t >= ofs) ? lds[t - ofs] : 0;
    __syncthreads();
    lds[t] += x;
    __syncthreads();
  }
  int excl = (t > 0) ? lds[t - 1] : 0;
  if (t < nb) bsum[t] = excl;
}

// ---------------------------------------------------------------------------
// scatter: pure permute, NO atomics, NO exp. edges2[p] = {src, bits(w)}.
// Plain loads (inputs are L2/L3-warm from k_fused; nt hurt here — R14).
__global__ void k_scatter(const int* __restrict__ ei, const float* __restrict__ w,
                          const int* __restrict__ off, const int* __restrict__ bsum,
                          const unsigned short* __restrict__ rank,
                          int2* __restrict__ edges2, int E) {
  int e = blockIdx.x * blockDim.x + threadIdx.x;
  if (e >= E) return;
  int s = ei[e], d = ei[E + e];
  int p = off[d] + bsum[d >> 10] + (int)rank[e];
  edges2[p] = make_int2(s, __float_as_int(w[e]));
}

// ---------------------------------------------------------------------------
// gather-aggregate: ONE wave per node; lane owns channels (2t,2t+1).
// 16-padded segments (R12-proven structure). Stage loads non-temporal
// (streamed once); out stores non-temporal (never re-read) -> keep L2 for h.
__global__ __launch_bounds__(256) void k_gather(
    const int2* __restrict__ edges2,
    const int* __restrict__ off, const int* __restrict__ bsum,
    const unsigned* __restrict__ cnt,
    const float* __restrict__ a_src, const float* __restrict__ a_dst,
    const unsigned short* __restrict__ hbf, const float* __restrict__ bias,
    float* __restrict__ out, int n) {
  int node = blockIdx.x * 4 + (threadIdx.x >> 6);
  if (node >= n) return;
  int t = threadIdx.x & 63;
  int j2 = t * 2;          // output channels j2, j2+1 (head hh = t>>4)
  int hh = t >> 4;
  int t15 = t & 15, q = t >> 2, h4 = t & 3;
  int beg = off[node] + bsum[node >> 10];
  int deg = (int)cnt[node];
  int end = beg + ((deg + 15) & ~15);

  float adq = a_dst[node * NH + h4];   // a_dst for head (t&3) (exp path)
  unsigned us = *(const unsigned*)(hbf + (size_t)node * HC + j2);
  float a_s_self = a_src[node * NH + hh];
  float a_d_self = a_dst[node * NH + hh];
  float acc0 = 0.f, acc1 = 0.f, den = 0.f, wacc = 0.f;

  const unsigned long long* e8 = (const unsigned long long*)edges2;
  for (int c = beg; c < end; c += 16) {
    unsigned long long evu = __builtin_nontemporal_load(e8 + c + t15);
    int evx = (int)(unsigned)(evu & 0xffffffffull);
    int evy = (int)(unsigned)(evu >> 32);
    int sq = __shfl(evx, q, 64);                       // src of edge c+(t>>2)
    float wq = __int_as_float(__shfl(evy, q, 64));
    float asq = a_src[sq * NH + h4];
    float et = expf(leaky(asq + adq) + log2f(wq));     // dummy: w=0 -> et=0
    wacc += (h4 == 0) ? wq : 0.f;
#pragma unroll
    for (int j = 0; j < 16; ++j) {
      int s = __shfl(evx, j, 64);
      float e = __shfl(et, j * 4 + hh, 64);
      unsigned u = *(const unsigned*)(hbf + (size_t)s * HC + j2);
      den += e;
      acc0 = fmaf(e, bf_lo(u), acc0);
      acc1 = fmaf(e, bf_hi(u), acc1);
    }
  }

  // wsum across wave (each real edge counted once by its (t&3)==0 lane)
#pragma unroll
  for (int m = 1; m <= 32; m <<= 1) wacc += __shfl_xor(wacc, m, 64);

  float lw = deg > 0 ? wacc / (float)deg : 1.f;
  float exs = expf(leaky(a_s_self + a_d_self) + log2f(lw));
  den += exs;
  acc0 = fmaf(exs, bf_lo(us), acc0);
  acc1 = fmaf(exs, bf_hi(us), acc1);
  float rden = 1.f / den;
  float o0 = acc0 * rden + bias[j2];
  float o1 = acc1 * rden + bias[j2 + 1];
  float* op = out + (size_t)node * HC + j2;
  __builtin_nontemporal_store(o0, op);
  __builtin_nontemporal_store(o1, op + 1);
}

// ---------------------------------------------------------------------------
extern "C" void kernel_launch(void* const* d_in, const int* in_sizes, int n_in,
                              void* d_out, int out_size, void* d_ws, size_t ws_size,
                              hipStream_t stream) {
  const float* x       = (const float*)d_in[0];
  const int*   ei      = (const int*)d_in[1];   // [2][E]
  const float* eattr   = (const float*)d_in[2];
  const float* W       = (const float*)d_in[3];
  const float* att_src = (const float*)d_in[4];
  const float* att_dst = (const float*)d_in[5];
  const float* bias    = (const float*)d_in[6];
  float* out = (float*)d_out;

  const int n = in_sizes[0] / DIN;
  const int E = in_sizes[2];
  const size_t EPAD = (size_t)E + (size_t)n * 15;   // upper bound on padded slots

  // workspace layout (all boundaries 8/16B aligned: n, E even)
  unsigned short* hbf = (unsigned short*)d_ws;            // n*HC bf16 (25.6 MB)
  int2*   edges2 = (int2*)(hbf + (size_t)n * HC);         // EPAD int2 (~24.8 MB)
  float*  a_src  = (float*)(edges2 + EPAD);               // n*4
  float*  a_dst  = a_src + (size_t)n * NH;                // n*4
  short*  bswz   = (short*)(a_dst + (size_t)n * NH);      // 16384 bf16 (32 KB)
  unsigned* cnt  = (unsigned*)(bswz + 16384);             // n u32
  int*    off    = (int*)(cnt + n);                       // n
  unsigned short* rank = (unsigned short*)(off + n);      // E u16
  int*    bsum   = (int*)(rank + E);                      // <=256

  const int* dst_idx = ei + E;
  int nb = (n + 1023) / 1024;
  int wavetiles = n >> 4;                 // n % 16 == 0
  int PB = (wavetiles + 3) / 4;           // proj blocks (4 waves each)
  int PB3 = ((PB + 2) / 3) * 3;
  int CB = 2 * (PB3 / 3);                 // count blocks (3:2 interleave)
  int grid = PB3 + CB;

  hipMemsetAsync(edges2, 0, EPAD * sizeof(int2), stream);  // dummy edges = {0, 0.0f}
  k_init<<<(n + 255) / 256, 256, 0, stream>>>(W, bswz, cnt, n);
  k_fused<<<grid, 256, 0, stream>>>(x, bswz, att_src, att_dst, hbf, a_src, a_dst, n,
                                    dst_idx, cnt, rank, E, CB);
  k_scan1<<<nb, 256, 0, stream>>>(cnt, off, bsum, n);
  k_scan2<<<1, 256, 0, stream>>>(bsum, nb);
  k_scatter<<<(E + 255) / 256, 256, 0, stream>>>(ei, eattr, off, bsum, rank, edges2, E);
  k_gather<<<(n + 3) / 4, 256, 0, stream>>>(edges2, off, bsum, cnt, a_src, a_dst,
                                            hbf, bias, out, n);
}